// Round 3
// baseline (435.688 us; speedup 1.0000x reference)
//
#include <hip/hip_runtime.h>
#include <hip/hip_bf16.h>

// SmoothnessConstraint: out[b,0,:]=x[b,0,:]; out[b,t,:]=out[b,t-1,:]+clip(x[b,t,:]-x[b,t-1,:],-0.5,0.5)
// B=4096, T=256, A=64, fp32. Parallel prefix over T (clipped diffs are state-free).
//
// MEASUREMENT NOTE (R1/R2 post-mortem): reported dur_us (~435) includes ~290 us of
// harness reset work (1 GiB ws poison ~165 us + d_out poison ~41 us + d_in restore
// ~83 us) -- our kernel dispatch is <165 us (absent from top-5). Optimize the
// kernel slice (~145 us in R2); HBM floor for 537 MB is ~85 us.
//
// R3 structure: block = 256 threads = 4 waves, owns (b, half-of-A): 8 float4 cols
// x 256 timesteps. thread = (a4 in [0,8), seg in [0,32)), SEG=8 rows each.
//   - SEG=8 -> v[8] = 32 data VGPRs; __launch_bounds__(256,8) caps at 64 VGPR
//     -> 8 waves/SIMD, 8 blocks/CU resident (vs 4 in R2): finer phase interleave.
//   - segment-boundary raw value exchanged via LDS (no global re-read, no extra
//     dependent vmem): traffic = pure 268 MB read + 268 MB write.

__device__ __forceinline__ float clip05(float d) {
    return fminf(fmaxf(d, -0.5f), 0.5f);
}

__global__ __launch_bounds__(256, 8) void smooth_scan(
    const float* __restrict__ in, float* __restrict__ out) {
    constexpr int T    = 256;
    constexpr int R4   = 16;   // full row (A=64) in float4
    constexpr int SEG  = 8;    // timesteps per thread
    constexpr int NSEG = 32;   // T / SEG
    constexpr int AH   = 8;    // float4 columns per half-A block

    __shared__ float4 lds_x0[AH];           // raw x[b,0,cols]
    __shared__ float4 lds_last[NSEG][AH];   // raw x at last row of each segment
    __shared__ float4 lds_tot[NSEG][AH];    // clipped-diff total per segment

    const int bh  = blockIdx.x;
    const int b   = bh >> 1;
    const int hf  = bh & 1;
    const int a4  = threadIdx.x & (AH - 1);
    const int seg = threadIdx.x >> 3;

    const size_t base = ((size_t)b * T + (size_t)seg * SEG) * R4 + (size_t)hf * AH + a4;
    const float4* __restrict__ ip = (const float4*)in + base;
    float4*       __restrict__ op = (float4*)out + base;

    // Batch of 8 independent float4 loads (128 B contiguous per 8-lane group).
    float4 v[SEG];
#pragma unroll
    for (int i = 0; i < SEG; ++i) v[i] = ip[i * R4];

    // Publish raw boundary values before in-place overwrite.
    lds_last[seg][a4] = v[SEG - 1];
    if (seg == 0) lds_x0[a4] = v[0];
    __syncthreads();

    // prev = raw element preceding this segment (seg 0: prev=v[0] -> d[0]=0).
    float4 prev = (seg != 0) ? lds_last[seg - 1][a4] : v[0];

    // In-place local inclusive prefix of clipped diffs.
    float4 run = make_float4(0.f, 0.f, 0.f, 0.f);
#pragma unroll
    for (int i = 0; i < SEG; ++i) {
        const float4 cur = v[i];
        run.x += clip05(cur.x - prev.x);
        run.y += clip05(cur.y - prev.y);
        run.z += clip05(cur.z - prev.z);
        run.w += clip05(cur.w - prev.w);
        prev = cur;
        v[i] = run;
    }

    lds_tot[seg][a4] = run;
    __syncthreads();

    // Offset = x[b,0] + sum of earlier segment totals (broadcast-friendly reads:
    // lanes sharing a4 read the same address; 8 distinct float4 = 2-way alias, free).
    float4 off = lds_x0[a4];
    for (int s = 0; s < seg; ++s) {
        const float4 t = lds_tot[s][a4];
        off.x += t.x; off.y += t.y; off.z += t.z; off.w += t.w;
    }

#pragma unroll
    for (int i = 0; i < SEG; ++i) {
        const float4 r = v[i];
        op[i * R4] = make_float4(off.x + r.x, off.y + r.y, off.z + r.z, off.w + r.w);
    }
}

extern "C" void kernel_launch(void* const* d_in, const int* in_sizes, int n_in,
                              void* d_out, int out_size, void* d_ws, size_t ws_size,
                              hipStream_t stream) {
    const float* in = (const float*)d_in[0];
    float* out = (float*)d_out;

    constexpr int B = 4096;
    smooth_scan<<<B * 2, 256, 0, stream>>>(in, out);
}

// Round 4
// 419.906 us; speedup vs baseline: 1.0376x; 1.0376x over previous
//
#include <hip/hip_runtime.h>
#include <hip/hip_bf16.h>

// SmoothnessConstraint: out[b,0,:]=x[b,0,:]; out[b,t,:]=out[b,t-1,:]+clip(x[b,t,:]-x[b,t-1,:],-0.5,0.5)
// B=4096, T=256, A=64, fp32. Parallel prefix over T (clipped diffs are state-free).
//
// MEASUREMENT MODEL (R0-R2 post-mortem): dur_us ~435 was IDENTICAL (+-0.1%) across
// three structurally different kernels -> kernel slice (~145 us) is invariant to
// occupancy/ILP structure. Harness fixed cost ~291 us (1 GiB ws poison 165 us
// [measured], d_out poison ~41 us, d_in restore ~85 us). Kernel runs ~3.7 TB/s
// effective vs 6.3-6.5 TB/s proven achievable by fills/copies on this chip.
//
// R4 single change: NONTEMPORAL loads+stores. Both 256 MiB streams are touch-once;
// default cache-allocating accesses thrash the 32 MiB L2 with eviction traffic
// interleaved into the demand stream. __builtin_nontemporal_{load,store} sets the
// nt bit (gfx950 MUBUF/FLAT) -> no L1/L2 allocation, pure streaming like the
// 6.29 TB/s copy ubench regime.

typedef float v4f __attribute__((ext_vector_type(4)));

__device__ __forceinline__ float clip05(float d) {
    return fminf(fmaxf(d, -0.5f), 0.5f);
}

__global__ __launch_bounds__(256, 8) void smooth_scan(
    const float* __restrict__ in, float* __restrict__ out) {
    constexpr int T    = 256;
    constexpr int R4   = 16;   // full row (A=64) in float4
    constexpr int SEG  = 8;    // timesteps per thread
    constexpr int NSEG = 32;   // T / SEG
    constexpr int AH   = 8;    // float4 columns per half-A block

    __shared__ v4f lds_x0[AH];           // raw x[b,0,cols]
    __shared__ v4f lds_last[NSEG][AH];   // raw x at last row of each segment
    __shared__ v4f lds_tot[NSEG][AH];    // clipped-diff total per segment

    const int bh  = blockIdx.x;
    const int b   = bh >> 1;
    const int hf  = bh & 1;
    const int a4  = threadIdx.x & (AH - 1);
    const int seg = threadIdx.x >> 3;

    const size_t base = ((size_t)b * T + (size_t)seg * SEG) * R4 + (size_t)hf * AH + a4;
    const v4f* __restrict__ ip = (const v4f*)in + base;
    v4f*       __restrict__ op = (v4f*)out + base;

    // 8 independent nontemporal float4 loads (128 B contiguous per 8-lane group).
    v4f v[SEG];
#pragma unroll
    for (int i = 0; i < SEG; ++i) v[i] = __builtin_nontemporal_load(ip + i * R4);

    // Publish raw boundary values before in-place overwrite.
    lds_last[seg][a4] = v[SEG - 1];
    if (seg == 0) lds_x0[a4] = v[0];
    __syncthreads();

    // prev = raw element preceding this segment (seg 0: prev=v[0] -> d[0]=0).
    v4f prev = (seg != 0) ? lds_last[seg - 1][a4] : v[0];

    // In-place local inclusive prefix of clipped diffs.
    v4f run = (v4f){0.f, 0.f, 0.f, 0.f};
#pragma unroll
    for (int i = 0; i < SEG; ++i) {
        const v4f cur = v[i];
        run.x += clip05(cur.x - prev.x);
        run.y += clip05(cur.y - prev.y);
        run.z += clip05(cur.z - prev.z);
        run.w += clip05(cur.w - prev.w);
        prev = cur;
        v[i] = run;
    }

    lds_tot[seg][a4] = run;
    __syncthreads();

    // Offset = x[b,0] + sum of earlier segment totals (LDS reads: 8 distinct
    // float4 rows -> worst 2-way bank alias, free).
    v4f off = lds_x0[a4];
    for (int s = 0; s < seg; ++s) off += lds_tot[s][a4];

    // Nontemporal streaming stores.
#pragma unroll
    for (int i = 0; i < SEG; ++i)
        __builtin_nontemporal_store(off + v[i], op + i * R4);
}

extern "C" void kernel_launch(void* const* d_in, const int* in_sizes, int n_in,
                              void* d_out, int out_size, void* d_ws, size_t ws_size,
                              hipStream_t stream) {
    const float* in = (const float*)d_in[0];
    float* out = (float*)d_out;

    constexpr int B = 4096;
    smooth_scan<<<B * 2, 256, 0, stream>>>(in, out);
}

// Round 5
// 419.180 us; speedup vs baseline: 1.0394x; 1.0017x over previous
//
#include <hip/hip_runtime.h>
#include <hip/hip_bf16.h>

// SmoothnessConstraint: out[b,0,:]=x[b,0,:]; out[b,t,:]=out[b,t-1,:]+clip(x[b,t,:]-x[b,t-1,:],-0.5,0.5)
// B=4096, T=256, A=64, fp32. Parallel prefix over T (clipped diffs are state-free).
//
// MEASUREMENT MODEL (R0-R4): reported dur_us includes ~290 us of harness resets;
// kernel slice ~130 us (nt hints bought -16 us in R4). Kernel runs ~4.2 TB/s vs
// 6.3-6.5 TB/s proven by fills/copies. All prior rounds issued wave-instructions
// scattering into 4-8 x 128-256 B chunks; the 6.3 TB/s regime is 1 KB contiguous
// per wave-instruction. R5 tests that hypothesis directly:
//
//   - Block = one b: 64 KB tile staged through LDS.
//   - Phase 1: 16 fully-coalesced nt loads/thread (f = tid + 256k) -> LDS.
//     Every global load instr covers 1 KB contiguous; k-sequence is sequential.
//   - Phase 2: thread (a4=tid&15, seg=tid>>4) runs a 16-step clipped-diff prefix
//     down its LDS column (8-way bank aliased -> ~2.9x on these ds ops; needed
//     LDS BW ~11 TB/s << 69 TB/s ceiling, hides under the global phases).
//   - Phase 3: per-segment offsets (x0 + prior segment totals) into a 4 KB table.
//   - Phase 4: 16 fully-coalesced nt stores of tile[f] + off[seg(f)][a4(f)].
//     (per store instr, seg(f)=k is uniform, off read is broadcast -> free)
//
// LDS 72 KB -> 2 blocks/CU; 4096 blocks.

typedef float v4f __attribute__((ext_vector_type(4)));

__device__ __forceinline__ float clip05(float d) {
    return fminf(fmaxf(d, -0.5f), 0.5f);
}

__device__ __forceinline__ v4f clipdiff(v4f a, v4f b) {   // clip(a - b, +-0.5)
    v4f r;
    r.x = clip05(a.x - b.x);
    r.y = clip05(a.y - b.y);
    r.z = clip05(a.z - b.z);
    r.w = clip05(a.w - b.w);
    return r;
}

__global__ __launch_bounds__(256) void smooth_scan(
    const float* __restrict__ in, float* __restrict__ out) {
    constexpr int T  = 256;
    constexpr int A4 = 16;          // float4 per timestep row
    constexpr int NV = T * A4;      // 4096 float4 per b

    __shared__ v4f tile[NV];        // 64 KB staging + in-place local prefixes
    __shared__ v4f tot[16][A4];     // per-segment clipped-diff totals
    __shared__ v4f offt[16][A4];    // per-segment output offsets

    const int tid = threadIdx.x;
    const size_t base = (size_t)blockIdx.x * NV;
    const v4f* __restrict__ ip = (const v4f*)in + base;
    v4f*       __restrict__ op = (v4f*)out + base;

    // Phase 1: fully-coalesced staging. 16 independent nt loads in flight/thread.
#pragma unroll
    for (int k = 0; k < 16; ++k)
        tile[tid + 256 * k] = __builtin_nontemporal_load(ip + tid + 256 * k);
    __syncthreads();

    // Phase 2: boundary reads (other threads' rows) BEFORE any overwrite.
    const int a4  = tid & 15;
    const int seg = tid >> 4;
    const v4f first = tile[a4];                                    // raw x[b,0,a4]
    v4f prev = (seg == 0) ? first : tile[(seg * 16 - 1) * A4 + a4]; // raw x before seg
    __syncthreads();

    // In-place local inclusive prefix of clipped diffs down this thread's column.
    v4f run = (v4f){0.f, 0.f, 0.f, 0.f};
#pragma unroll
    for (int i = 0; i < 16; ++i) {
        const int idx = (seg * 16 + i) * A4 + a4;
        const v4f cur = tile[idx];
        run += clipdiff(cur, prev);
        prev = cur;
        tile[idx] = run;
    }
    tot[seg][a4] = run;
    __syncthreads();

    // Phase 3: segment offset = x[b,0] + totals of earlier segments.
    v4f off = first;
    for (int s = 0; s < seg; ++s) off += tot[s][a4];
    offt[seg][a4] = off;
    __syncthreads();

    // Phase 4: fully-coalesced nt stores; seg(f) == k is wave-uniform per step,
    // offt read is a 16-address broadcast (free).
#pragma unroll
    for (int k = 0; k < 16; ++k) {
        const int f = tid + 256 * k;
        __builtin_nontemporal_store(tile[f] + offt[k][tid & 15], op + f);
    }
}

extern "C" void kernel_launch(void* const* d_in, const int* in_sizes, int n_in,
                              void* d_out, int out_size, void* d_ws, size_t ws_size,
                              hipStream_t stream) {
    const float* in = (const float*)d_in[0];
    float* out = (float*)d_out;

    constexpr int B = 4096;
    smooth_scan<<<B, 256, 0, stream>>>(in, out);
}